// Round 1
// baseline (2153.571 us; speedup 1.0000x reference)
//
#include <hip/hip_runtime.h>

#define NN 100000
#define NE 1200000
#define D 64
#define NPB 64

// ---------------------------------------------------------------------------
// Scatter: for each edge e, agg[dst[e]][:] += feat[src[e]][:]; deg[dst[e]] += 1
// 16 lanes per edge, float4 per lane (64 floats = one row).
// ---------------------------------------------------------------------------
__global__ __launch_bounds__(256) void sage_scatter(
    const float* __restrict__ feat,
    const int* __restrict__ src,
    const int* __restrict__ dst,
    float* __restrict__ agg,
    float* __restrict__ deg,
    int E, int count_deg) {
  int t = blockIdx.x * blockDim.x + threadIdx.x;
  int e = t >> 4;
  if (e >= E) return;
  int lane = t & 15;
  int s = src[e];
  int d = dst[e];
  float4 v = ((const float4*)(feat + (size_t)s * D))[lane];
  float* drow = agg + (size_t)d * D + lane * 4;
  atomicAdd(drow + 0, v.x);
  atomicAdd(drow + 1, v.y);
  atomicAdd(drow + 2, v.z);
  atomicAdd(drow + 3, v.w);
  if (count_deg && lane == 0) atomicAdd(deg + d, 1.0f);
}

// ---------------------------------------------------------------------------
// Transform: out[i][c] = relu?( (agg[i]/max(deg,1)) . Wl[c][:] + x[i] . Wr[c][:] + b[c] )
// One wave per node; weights in LDS padded to stride 68 (17 float4) so the
// per-lane ds_read_b128 at float4-index c*17+j is conflict-free (odd mult).
// ---------------------------------------------------------------------------
__global__ __launch_bounds__(256) void sage_transform(
    const float* __restrict__ aggsum,
    const float* __restrict__ deg,
    const float* __restrict__ xin,
    const float* __restrict__ Wl,
    const float* __restrict__ Wr,
    const float* __restrict__ bias,
    float* __restrict__ out,
    int N, int do_relu) {
  __shared__ __align__(16) float WlS[D * 68];
  __shared__ __align__(16) float WrS[D * 68];
  __shared__ float bS[D];
  __shared__ __align__(16) float rowA[4][D];
  __shared__ __align__(16) float rowX[4][D];

  int tid = threadIdx.x;
  for (int i = tid; i < D * D; i += 256) {
    int c = i >> 6, k = i & 63;
    WlS[c * 68 + k] = Wl[i];
    WrS[c * 68 + k] = Wr[i];
  }
  if (tid < D) bS[tid] = bias[tid];
  __syncthreads();

  int wave = tid >> 6;
  int c = tid & 63;
  int base = blockIdx.x * NPB;

  for (int n0 = wave; n0 < NPB; n0 += 4) {
    int node = base + n0;
    if (node >= N) break;
    float inv = 1.0f / fmaxf(deg[node], 1.0f);
    rowA[wave][c] = aggsum[(size_t)node * D + c] * inv;
    rowX[wave][c] = xin[(size_t)node * D + c];
    __builtin_amdgcn_wave_barrier();  // wave-synchronous LDS handoff

    const float4* a4 = (const float4*)rowA[wave];
    const float4* x4 = (const float4*)rowX[wave];
    const float4* wl4 = (const float4*)(WlS + c * 68);
    const float4* wr4 = (const float4*)(WrS + c * 68);
    float acc = bS[c];
#pragma unroll
    for (int j = 0; j < 16; ++j) {
      float4 a = a4[j], x = x4[j], wl = wl4[j], wr = wr4[j];
      acc += a.x * wl.x + a.y * wl.y + a.z * wl.z + a.w * wl.w;
      acc += x.x * wr.x + x.y * wr.y + x.z * wr.z + x.w * wr.w;
    }
    if (do_relu) acc = fmaxf(acc, 0.0f);
    out[(size_t)node * D + c] = acc;
    __builtin_amdgcn_wave_barrier();  // keep next iter's ds_writes behind reads
  }
}

extern "C" void kernel_launch(void* const* d_in, const int* in_sizes, int n_in,
                              void* d_out, int out_size, void* d_ws, size_t ws_size,
                              hipStream_t stream) {
  const float* x   = (const float*)d_in[0];
  const int* edge  = (const int*)d_in[1];
  const float* W1l = (const float*)d_in[2];
  const float* W1r = (const float*)d_in[3];
  const float* b1  = (const float*)d_in[4];
  const float* W2l = (const float*)d_in[5];
  const float* W2r = (const float*)d_in[6];
  const float* b2  = (const float*)d_in[7];
  float* out = (float*)d_out;

  const int N = NN, E = NE;
  const int* src = edge;        // edge_index[0]
  const int* dst = edge + E;    // edge_index[1]

  // workspace layout: deg [N] | agg [N*D] | h [N*D]  (~51.6 MB)
  float* deg = (float*)d_ws;
  float* agg = deg + N;
  float* h   = agg + (size_t)N * D;

  // zero deg + agg (contiguous)
  hipMemsetAsync(deg, 0, (size_t)(N + (size_t)N * D) * sizeof(float), stream);

  int gridS = (E * 16 + 255) / 256;
  int gridT = (N + NPB - 1) / NPB;

  // ---- layer 1 ----
  sage_scatter<<<gridS, 256, 0, stream>>>(x, src, dst, agg, deg, E, 1);
  sage_transform<<<gridT, 256, 0, stream>>>(agg, deg, x, W1l, W1r, b1, h, N, 1);

  // ---- layer 2 ----
  hipMemsetAsync(agg, 0, (size_t)N * D * sizeof(float), stream);
  sage_scatter<<<gridS, 256, 0, stream>>>(h, src, dst, agg, deg, E, 0);
  sage_transform<<<gridT, 256, 0, stream>>>(agg, deg, h, W2l, W2r, b2, out, N, 0);
}

// Round 2
// 398.897 us; speedup vs baseline: 5.3988x; 5.3988x over previous
//
#include <hip/hip_runtime.h>

#define NN 100000
#define NE 1200000
#define D 64
#define NPB 64

// ---------------------------------------------------------------------------
// CSR build: histogram of dst, exclusive scan, fill edge list.
// ---------------------------------------------------------------------------
__global__ __launch_bounds__(256) void k_hist(const int* __restrict__ dst,
                                              int* __restrict__ deg, int E) {
  int e = blockIdx.x * blockDim.x + threadIdx.x;
  if (e < E) atomicAdd(&deg[dst[e]], 1);
}

__global__ __launch_bounds__(256) void k_blocksum(const int* __restrict__ deg,
                                                  int* __restrict__ bsum, int N) {
  __shared__ int s[256];
  int t = threadIdx.x;
  int i = blockIdx.x * 256 + t;
  s[t] = (i < N) ? deg[i] : 0;
  __syncthreads();
  for (int o = 128; o > 0; o >>= 1) {
    if (t < o) s[t] += s[t + o];
    __syncthreads();
  }
  if (t == 0) bsum[blockIdx.x] = s[0];
}

// single-block exclusive scan over up to 1024 block sums
__global__ __launch_bounds__(1024) void k_scan_bsum(int* bsum, int NB) {
  __shared__ int s[1024];
  int t = threadIdx.x;
  int v = (t < NB) ? bsum[t] : 0;
  s[t] = v;
  __syncthreads();
  for (int o = 1; o < 1024; o <<= 1) {
    int add = (t >= o) ? s[t - o] : 0;
    __syncthreads();
    s[t] += add;
    __syncthreads();
  }
  if (t < NB) bsum[t] = s[t] - v;  // exclusive
}

__global__ __launch_bounds__(256) void k_offsets(const int* __restrict__ deg,
                                                 const int* __restrict__ bsum,
                                                 int* __restrict__ off, int N) {
  __shared__ int s[256];
  int t = threadIdx.x;
  int i = blockIdx.x * 256 + t;
  int v = (i < N) ? deg[i] : 0;
  s[t] = v;
  __syncthreads();
  for (int o = 1; o < 256; o <<= 1) {
    int add = (t >= o) ? s[t - o] : 0;
    __syncthreads();
    s[t] += add;
    __syncthreads();
  }
  if (i < N) off[i] = bsum[blockIdx.x] + s[t] - v;  // exclusive
}

__global__ __launch_bounds__(256) void k_fill(const int* __restrict__ src,
                                              const int* __restrict__ dst,
                                              int* __restrict__ cur,
                                              int* __restrict__ eidx, int E) {
  int e = blockIdx.x * blockDim.x + threadIdx.x;
  if (e < E) {
    int d = dst[e];
    int p = atomicAdd(&cur[d], 1);
    eidx[p] = src[e];
  }
}

// ---------------------------------------------------------------------------
// Gather-aggregate: agg[i][:] = mean over incoming src rows. 16 lanes/node,
// each lane owns one float4 column slice; coalesced 256B row reads.
// ---------------------------------------------------------------------------
__global__ __launch_bounds__(256) void k_aggregate(const float* __restrict__ feat,
                                                   const int* __restrict__ off,
                                                   const int* __restrict__ deg,
                                                   const int* __restrict__ eidx,
                                                   float* __restrict__ agg, int N) {
  int t = blockIdx.x * 256 + threadIdx.x;
  int node = t >> 4;
  if (node >= N) return;
  int lane = t & 15;
  int start = off[node];
  int cnt = deg[node];
  float4 acc = {0.f, 0.f, 0.f, 0.f};
  for (int j = 0; j < cnt; ++j) {
    int s = eidx[start + j];
    float4 v = ((const float4*)(feat + (size_t)s * D))[lane];
    acc.x += v.x; acc.y += v.y; acc.z += v.z; acc.w += v.w;
  }
  float inv = 1.0f / fmaxf((float)cnt, 1.0f);
  acc.x *= inv; acc.y *= inv; acc.z *= inv; acc.w *= inv;
  ((float4*)(agg + (size_t)node * D))[lane] = acc;
}

// ---------------------------------------------------------------------------
// Transform: out[i][c] = relu?( agg[i] . Wl[c][:] + x[i] . Wr[c][:] + b[c] )
// agg is already the mean. aggsum/out may alias (layer-2 in-place) -> no
// __restrict__ on those.
// ---------------------------------------------------------------------------
__global__ __launch_bounds__(256) void sage_transform(
    const float* aggsum,
    const float* __restrict__ xin,
    const float* __restrict__ Wl,
    const float* __restrict__ Wr,
    const float* __restrict__ bias,
    float* out,
    int N, int do_relu) {
  __shared__ __align__(16) float WlS[D * 68];
  __shared__ __align__(16) float WrS[D * 68];
  __shared__ float bS[D];
  __shared__ __align__(16) float rowA[4][D];
  __shared__ __align__(16) float rowX[4][D];

  int tid = threadIdx.x;
  for (int i = tid; i < D * D; i += 256) {
    int c = i >> 6, k = i & 63;
    WlS[c * 68 + k] = Wl[i];
    WrS[c * 68 + k] = Wr[i];
  }
  if (tid < D) bS[tid] = bias[tid];
  __syncthreads();

  int wave = tid >> 6;
  int c = tid & 63;
  int base = blockIdx.x * NPB;

  for (int n0 = wave; n0 < NPB; n0 += 4) {
    int node = base + n0;
    if (node >= N) break;
    rowA[wave][c] = aggsum[(size_t)node * D + c];
    rowX[wave][c] = xin[(size_t)node * D + c];
    __builtin_amdgcn_wave_barrier();  // wave-synchronous LDS handoff

    const float4* a4 = (const float4*)rowA[wave];
    const float4* x4 = (const float4*)rowX[wave];
    const float4* wl4 = (const float4*)(WlS + c * 68);
    const float4* wr4 = (const float4*)(WrS + c * 68);
    float acc = bS[c];
#pragma unroll
    for (int j = 0; j < 16; ++j) {
      float4 a = a4[j], x = x4[j], wl = wl4[j], wr = wr4[j];
      acc += a.x * wl.x + a.y * wl.y + a.z * wl.z + a.w * wl.w;
      acc += x.x * wr.x + x.y * wr.y + x.z * wr.z + x.w * wr.w;
    }
    if (do_relu) acc = fmaxf(acc, 0.0f);
    out[(size_t)node * D + c] = acc;
    __builtin_amdgcn_wave_barrier();  // keep next iter's ds_writes behind reads
  }
}

extern "C" void kernel_launch(void* const* d_in, const int* in_sizes, int n_in,
                              void* d_out, int out_size, void* d_ws, size_t ws_size,
                              hipStream_t stream) {
  const float* x   = (const float*)d_in[0];
  const int* edge  = (const int*)d_in[1];
  const float* W1l = (const float*)d_in[2];
  const float* W1r = (const float*)d_in[3];
  const float* b1  = (const float*)d_in[4];
  const float* W2l = (const float*)d_in[5];
  const float* W2r = (const float*)d_in[6];
  const float* b2  = (const float*)d_in[7];
  float* out = (float*)d_out;

  const int N = NN, E = NE;
  const int* src = edge;        // edge_index[0]
  const int* dst = edge + E;    // edge_index[1]

  // workspace layout: deg[N] | off[N] | cur[N] | bsum[1024] | eidx[E] | h[N*D]
  int* deg  = (int*)d_ws;
  int* off  = deg + N;
  int* cur  = off + N;
  int* bsum = cur + N;
  int* eidx = bsum + 1024;
  float* h  = (float*)(eidx + E);

  const int NB = (N + 255) / 256;       // 391 blocks <= 1024
  const int gridE = (E + 255) / 256;
  const int gridA = (N * 16 + 255) / 256;
  const int gridT = (N + NPB - 1) / NPB;

  // ---- CSR build (shared by both layers) ----
  hipMemsetAsync(deg, 0, (size_t)N * sizeof(int), stream);
  k_hist<<<gridE, 256, 0, stream>>>(dst, deg, E);
  k_blocksum<<<NB, 256, 0, stream>>>(deg, bsum, N);
  k_scan_bsum<<<1, 1024, 0, stream>>>(bsum, NB);
  k_offsets<<<NB, 256, 0, stream>>>(deg, bsum, off, N);
  hipMemcpyAsync(cur, off, (size_t)N * sizeof(int), hipMemcpyDeviceToDevice, stream);
  k_fill<<<gridE, 256, 0, stream>>>(src, dst, cur, eidx, E);

  // ---- layer 1: aggregate x into d_out (scratch), transform -> h ----
  k_aggregate<<<gridA, 256, 0, stream>>>(x, off, deg, eidx, out, N);
  sage_transform<<<gridT, 256, 0, stream>>>(out, x, W1l, W1r, b1, h, N, 1);

  // ---- layer 2: aggregate h into d_out, transform in-place -> d_out ----
  k_aggregate<<<gridA, 256, 0, stream>>>(h, off, deg, eidx, out, N);
  sage_transform<<<gridT, 256, 0, stream>>>(out, h, W2l, W2r, b2, out, N, 0);
}